// Round 10
// baseline (189.234 us; speedup 1.0000x reference)
//
#include <hip/hip_runtime.h>
#include <hip/hip_fp16.h>

#define R_    1024
#define B_    4
#define C_    256
#define H_    64
#define W_    64
#define HW_   4096
#define PHW_  49
#define ROIT  128     // floats per per-ROI geometry record (512 B)
#define LROWF 258     // fixup LDS row halves (256 + 2 pad)
#define NTASK (R_ * 7)

__device__ __forceinline__ void cell_w(float start, float end, float s, float& g0, float& g1) {
    float y0 = fmaxf(start, s);
    float yl = fmaxf(fminf(end, s + 1.0f), y0);
    float a  = y0 - s;
    float la = yl - s;
    g0 = la - 0.5f * la * la - a + 0.5f * a * a;
    g1 = 0.5f * la * la - 0.5f * a * a;
}

__device__ __forceinline__ float4 h4_to_f4(uint2 u) {
    __half2 a = *reinterpret_cast<__half2*>(&u.x);
    __half2 b = *reinterpret_cast<__half2*>(&u.y);
    float2 fa = __half22float2(a);
    float2 fb = __half22float2(b);
    return make_float4(fa.x, fa.y, fb.x, fb.y);
}

// ---- prep: transpose (B,C,H,W) f32 -> (B,H*W,C) f16 [0..4095]
//            + ROI work-sort & counter-zero [4096] + per-ROI geometry [4097..4292] ----
__global__ __launch_bounds__(256) void prep(const float* __restrict__ in,
                                            __half* __restrict__ fTh,
                                            const float* __restrict__ rois,
                                            int* __restrict__ perm,
                                            float* __restrict__ roitab,
                                            int* __restrict__ cnt) {
    int bid = blockIdx.x;
    if (bid < 4096) {
        __shared__ float tile[32][33];
        int b   = bid >> 10;
        int rem = bid & 1023;
        int c0  = (rem >> 7) * 32;
        int p0  = (rem & 127) * 32;
        int tx  = threadIdx.x & 31;
        int ty  = threadIdx.x >> 5;
        const float* src = in + (size_t)b * C_ * HW_;
#pragma unroll
        for (int i = 0; i < 32; i += 8)
            tile[ty + i][tx] = src[(size_t)(c0 + ty + i) * HW_ + (p0 + tx)];
        __syncthreads();
        __half2* dsth = (__half2*)(fTh + (size_t)b * HW_ * C_);
#pragma unroll
        for (int i = 0; i < 2; ++i) {
            int idx = threadIdx.x + i * 256;
            int py  = idx >> 4;
            int cp  = idx & 15;
            float lo = tile[cp * 2][py];
            float hi = tile[cp * 2 + 1][py];
            dsth[(size_t)(p0 + py) * (C_ / 2) + (c0 >> 1) + cp] = __floats2half2_rn(lo, hi);
        }
        return;
    }
    if (bid == 4096) {
        if (threadIdx.x >= 64) {
            if (threadIdx.x == 64) cnt[0] = 0;   // zero the task queue each launch
            return;
        }
        // 1 wave: ballot-based stable counting sort by DESCENDING work estimate.
        // Biggest tasks first -> LPT scheduling through the queue. Deterministic.
        int lane = threadIdx.x;
        unsigned long long below = (1ull << lane) - 1ull;
        int key[16];
#pragma unroll
        for (int i = 0; i < 16; ++i) {
            int idx = i * 64 + lane;
            const float* roi = rois + idx * 5;
            float rwc = fmaxf((roi[3] - roi[1]) * 0.0625f, 0.0f);
            float bh  = fmaxf((roi[4] - roi[2]) * 0.0625f, 0.0f) * (1.0f / 7.0f);
            float work = (rwc + 2.0f) * (bh + 2.0f);     // ~ jlim * rows-per-bin
            int kq = (int)(work * (15.0f / 180.0f));
            key[i] = 15 - min(15, max(0, kq));           // 0 = biggest
        }
        int cntk[16];
#pragma unroll
        for (int k = 0; k < 16; ++k) cntk[k] = 0;
        for (int i = 0; i < 16; ++i)
#pragma unroll
            for (int k = 0; k < 16; ++k)
                cntk[k] += __popcll(__ballot(key[i] == k));
        int off[16]; int acc = 0;
#pragma unroll
        for (int k = 0; k < 16; ++k) { off[k] = acc; acc += cntk[k]; }
        for (int i = 0; i < 16; ++i) {
#pragma unroll
            for (int k = 0; k < 16; ++k) {
                unsigned long long m = __ballot(key[i] == k);
                if (key[i] == k)
                    perm[off[k] + __popcll(m & below)] = i * 64 + lane;
                off[k] += __popcll(m);
            }
        }
        return;
    }
    // per-bin geometry -> scatter into per-ROI record
    int i = (bid - 4097) * 256 + threadIdx.x;   // 0..50175
    int r  = i / PHW_;
    int k  = i - r * PHW_;
    int ph = k / 7, pw = k - ph * 7;
    const float* roi = rois + r * 5;
    int bb = (int)roi[0];
    float x1 = roi[1] * 0.0625f, y1 = roi[2] * 0.0625f;
    float x2 = roi[3] * 0.0625f, y2 = roi[4] * 0.0625f;
    float rw = fmaxf(x2 - x1, 0.0f), rh = fmaxf(y2 - y1, 0.0f);
    float bw = rw / 7.0f, bh = rh / 7.0f;
    float win = bw * bh;
    float* rt = roitab + (size_t)r * ROIT;

    float wy[7], wx[7];
#pragma unroll
    for (int t = 0; t < 7; ++t) { wy[t] = 0.0f; wx[t] = 0.0f; }
    int w0 = 0, h0 = 0, npy = 0, w00 = 0;
    float invwin = 0.0f;
    if (win > 0.0f) {
        float ws = x1 + bw * (float)pw, we = ws + bw;
        float hs = y1 + bh * (float)ph, he = hs + bh;
        float s0w = floorf(ws), s0h = floorf(hs);
        w0 = (int)s0w; h0 = (int)s0h;
        w00 = (int)floorf(x1);
#pragma unroll
        for (int o = 0; o < 6; ++o) {
            float g0, g1;
            cell_w(hs, he, s0h + (float)o, g0, g1);
            wy[o] += g0; wy[o + 1] += g1;
            cell_w(ws, we, s0w + (float)o, g0, g1);
            wx[o] += g0; wx[o + 1] += g1;
        }
        npy = min(7, max(0, (int)ceilf(he - s0h + 1.0f)));
        int npx = min(7, max(0, (int)ceilf(we - s0w + 1.0f)));
        npy = max(0, min(npy, H_ - h0));
        npx = max(0, min(npx, W_ - w0));
#pragma unroll
        for (int t = 0; t < 7; ++t) {
            if (t >= npx) wx[t] = 0.0f;
            if (t >= npy) wy[t] = 0.0f;
        }
        invwin = 1.0f / win;
    }
    if (ph == 0) {
#pragma unroll
        for (int t = 0; t < 7; ++t) rt[pw * 7 + t] = wx[t];
        rt[49 + pw] = __int_as_float(w0 - w00);
    }
    if (pw == 0) {
#pragma unroll
        for (int t = 0; t < 7; ++t) rt[72 + ph * 8 + t] = wy[t] * invwin;
        rt[64 + ph] = __int_as_float(h0 | (npy << 8));
    }
    if (k == 0) {
        int jlim = 0;
        if (win > 0.0f) {
#pragma unroll
            for (int p = 0; p < 7; ++p) {
                float wsp = x1 + bw * (float)p, wep = wsp + bw;
                float s0wp = floorf(wsp);
                int w0p = (int)s0wp;
                int npxp = min(7, max(0, (int)ceilf(wep - s0wp + 1.0f)));
                npxp = max(0, min(npxp, W_ - w0p));
                jlim = max(jlim, (w0p - w00) + npxp);
            }
        }
        rt[63] = __int_as_float(bb | (w00 << 8) | (jlim << 16));
    }
}

// ---- compute: persistent waves; each wave pops (ROI, bin-row) tasks from a global queue.
// Task order = descending work (LPT). Results independent of assignment -> deterministic.
__global__ __launch_bounds__(256) void prroi_rows(const __half* __restrict__ fTh,
                                                  const int* __restrict__ perm,
                                                  const float* __restrict__ roitab,
                                                  int* __restrict__ cnt,
                                                  __half* __restrict__ scr) {
    __shared__ float colw[4][32 * 8];   // per-wave 32 cols x {7 coef + pad}
    int wid  = __builtin_amdgcn_readfirstlane(threadIdx.x >> 6);
    int lane = threadIdx.x & 63;
    float* cwv = colw[wid];

    for (;;) {
        int t0 = 0;
        if (lane == 0) t0 = atomicAdd(cnt, 1);
        int t = __builtin_amdgcn_readfirstlane(__shfl(t0, 0, 64));
        if (t >= NTASK) break;
        int rs = t / 7;
        int ph = t - rs * 7;
        int r  = __builtin_amdgcn_readfirstlane(perm[rs]);
        const float* rt = roitab + (size_t)r * ROIT;

#pragma unroll
        for (int q = 0; q < 4; ++q) cwv[lane + q * 64] = 0.0f;
        if (lane < 49) {
            int pw = lane / 7;
            int dx = lane - pw * 7;
            float wxv = rt[lane];
            int d = __float_as_int(rt[49 + pw]);
            cwv[(d + dx) * 8 + pw] = wxv;   // unique (jl,pw) per lane; wave-internal order via lgkmcnt
        }
        int meta = __float_as_int(rt[63]);
        int bb   = meta & 0xff;
        int w00  = (meta >> 8) & 0xff;
        int jlim = (meta >> 16) & 0xff;
        int hm   = __float_as_int(rt[64 + ph]);
        int h0   = hm & 0xff;
        int npy  = (hm >> 8) & 0xff;

        float4 acc[7];
#pragma unroll
        for (int p = 0; p < 7; ++p) acc[p] = make_float4(0.f, 0.f, 0.f, 0.f);

        for (int dy = 0; dy < npy; ++dy) {             // wave-uniform bound
            float wyd = rt[72 + ph * 8 + dy];          // uniform -> scalar load
            const __half* rp = fTh + ((size_t)(bb * HW_ + (h0 + dy) * W_ + w00)) * C_ + lane * 4;
            float4 cacc[7];
#pragma unroll
            for (int p = 0; p < 7; ++p) cacc[p] = make_float4(0.f, 0.f, 0.f, 0.f);
            for (int jl = 0; jl < jlim; ++jl) {        // wave-uniform bound; 1 request/column
                uint2 v = *(const uint2*)(rp + (size_t)jl * C_);
                float4 f = h4_to_f4(v);
                const float* cw = cwv + jl * 8;
#pragma unroll
                for (int p = 0; p < 7; ++p) {
                    float c = cw[p];                   // broadcast ds_read
                    cacc[p].x = fmaf(c, f.x, cacc[p].x);
                    cacc[p].y = fmaf(c, f.y, cacc[p].y);
                    cacc[p].z = fmaf(c, f.z, cacc[p].z);
                    cacc[p].w = fmaf(c, f.w, cacc[p].w);
                }
            }
#pragma unroll
            for (int p = 0; p < 7; ++p) {
                acc[p].x = fmaf(wyd, cacc[p].x, acc[p].x);
                acc[p].y = fmaf(wyd, cacc[p].y, acc[p].y);
                acc[p].z = fmaf(wyd, cacc[p].z, acc[p].z);
                acc[p].w = fmaf(wyd, cacc[p].w, acc[p].w);
            }
        }
        __half* sb = scr + ((size_t)r * PHW_ + ph * 7) * C_ + lane * 4;
#pragma unroll
        for (int p = 0; p < 7; ++p) {
            union { __half2 h2[2]; uint2 u; } pk2;
            pk2.h2[0] = __floats2half2_rn(acc[p].x, acc[p].y);
            pk2.h2[1] = __floats2half2_rn(acc[p].z, acc[p].w);
            *(uint2*)(sb + (size_t)p * C_) = pk2.u;
        }
    }
}

// ---- fixup: per-ROI [k][c] f16 -> [c][k] f32 through padded LDS ----
__global__ __launch_bounds__(256) void fixup(const int* __restrict__ perm,
                                             const __half* __restrict__ scr,
                                             float* __restrict__ out) {
    __shared__ __align__(4) __half lds_h[PHW_ * LROWF];
    int bid  = blockIdx.x;
    int spos = ((bid & 7) << 7) | (bid >> 3);   // arbitrary bijection over sorted positions
    int r    = perm[spos];
    const unsigned int* src = (const unsigned int*)(scr + (size_t)r * PHW_ * C_);
    for (int j = threadIdx.x; j < PHW_ * (C_ / 2); j += 256) {
        int row = j >> 7;
        int col = j & 127;
        *(unsigned int*)&lds_h[row * LROWF + col * 2] = src[j];
    }
    __syncthreads();
    float* outr = out + (size_t)r * (C_ * PHW_);
#pragma unroll 4
    for (int j = threadIdx.x; j < C_ * PHW_; j += 256) {
        int c = j / PHW_;
        int k = j - c * PHW_;
        outr[j] = __half2float(lds_h[k * LROWF + c]);
    }
}

// ---- fallback: original layout, no workspace ----
__global__ __launch_bounds__(256) void prroi_pool_direct(const float* __restrict__ f,
                                                         const float* __restrict__ rois,
                                                         float* __restrict__ out) {
    int bin = blockIdx.x;
    int r  = bin / PHW_;
    int k  = bin - r * PHW_;
    int ph = k / 7;
    int pw = k - ph * 7;
    int c = threadIdx.x;

    const float* roi = rois + r * 5;
    int bb = (int)roi[0];
    float x1 = roi[1] * 0.0625f, y1 = roi[2] * 0.0625f;
    float x2 = roi[3] * 0.0625f, y2 = roi[4] * 0.0625f;
    float rw = fmaxf(x2 - x1, 0.0f), rh = fmaxf(y2 - y1, 0.0f);
    float bw = rw / 7.0f, bh = rh / 7.0f;
    float win = bw * bh;
    size_t oidx = ((size_t)r * C_ + c) * PHW_ + k;
    if (!(win > 0.0f)) { out[oidx] = 0.0f; return; }

    float ws = x1 + bw * (float)pw, we = ws + bw;
    float hs = y1 + bh * (float)ph, he = hs + bh;
    float s0w = floorf(ws), s0h = floorf(hs);
    int w0 = (int)s0w, h0 = (int)s0h;
    float wy[7], wx[7];
#pragma unroll
    for (int t = 0; t < 7; ++t) { wy[t] = 0.0f; wx[t] = 0.0f; }
#pragma unroll
    for (int o = 0; o < 6; ++o) {
        float g0, g1;
        cell_w(hs, he, s0h + (float)o, g0, g1);
        wy[o] += g0; wy[o + 1] += g1;
        cell_w(ws, we, s0w + (float)o, g0, g1);
        wx[o] += g0; wx[o + 1] += g1;
    }
    int npy = min(7, max(0, (int)ceilf(he - s0h + 1.0f)));
    int npx = min(7, max(0, (int)ceilf(we - s0w + 1.0f)));
    npy = max(0, min(npy, H_ - h0));
    npx = max(0, min(npx, W_ - w0));

    const float* fbc = f + ((size_t)bb * C_ + c) * (H_ * W_);
    float acc = 0.0f;
#pragma unroll
    for (int dy = 0; dy < 7; ++dy) {
        if (dy < npy) {
            float row = 0.0f;
#pragma unroll
            for (int dx = 0; dx < 7; ++dx) {
                if (dx < npx)
                    row = fmaf(wx[dx], fbc[(h0 + dy) * W_ + (w0 + dx)], row);
            }
            acc = fmaf(wy[dy], row, acc);
        }
    }
    out[oidx] = acc / win;
}

extern "C" void kernel_launch(void* const* d_in, const int* in_sizes, int n_in,
                              void* d_out, int out_size, void* d_ws, size_t ws_size,
                              hipStream_t stream) {
    const float* feat = (const float*)d_in[0];
    const float* rois = (const float*)d_in[1];
    float* out = (float*)d_out;

    const size_t fth_b  = (size_t)B_ * HW_ * C_ * sizeof(__half);     //  8,388,608
    const size_t perm_b = (size_t)R_ * sizeof(int);                   //      4,096
    const size_t rt_b   = (size_t)R_ * ROIT * sizeof(float);          //    524,288
    const size_t cnt_b  = 256;
    const size_t scr_b  = (size_t)R_ * PHW_ * C_ * sizeof(__half);    // 25,690,112

    if (ws_size >= fth_b + perm_b + rt_b + cnt_b + scr_b) {
        __half* fTh  = (__half*)d_ws;
        int*    perm = (int*)((char*)d_ws + fth_b);
        float*  rtab = (float*)((char*)d_ws + fth_b + perm_b);
        int*    cnt  = (int*)((char*)d_ws + fth_b + perm_b + rt_b);
        __half* scr  = (__half*)((char*)d_ws + fth_b + perm_b + rt_b + cnt_b);
        prep<<<4293, 256, 0, stream>>>(feat, fTh, rois, perm, rtab, cnt);
        prroi_rows<<<1024, 256, 0, stream>>>(fTh, perm, rtab, cnt, scr);
        fixup<<<R_, 256, 0, stream>>>(perm, scr, out);
    } else {
        prroi_pool_direct<<<R_ * PHW_, 256, 0, stream>>>(feat, rois, out);
    }
}

// Round 11
// 118.360 us; speedup vs baseline: 1.5988x; 1.5988x over previous
//
#include <hip/hip_runtime.h>
#include <hip/hip_fp16.h>

#define R_    1024
#define B_    4
#define C_    256
#define H_    64
#define W_    64
#define HW_   4096
#define PHW_  49
#define ROIT  128     // floats per per-ROI geometry record (512 B)
#define LROWF 258     // fixup LDS row halves (256 + 2 pad)
#define NTASK (R_ * 7)
#define TPX   (NTASK / 8)   // tasks per XCD chunk = 896
#define SLACKH 2048         // zeroed halves after fTh (guards paired-load overrun)

__device__ __forceinline__ void cell_w(float start, float end, float s, float& g0, float& g1) {
    float y0 = fmaxf(start, s);
    float yl = fmaxf(fminf(end, s + 1.0f), y0);
    float a  = y0 - s;
    float la = yl - s;
    g0 = la - 0.5f * la * la - a + 0.5f * a * a;
    g1 = 0.5f * la * la - 0.5f * a * a;
}

__device__ __forceinline__ float4 h4_to_f4(uint2 u) {
    __half2 a = *reinterpret_cast<__half2*>(&u.x);
    __half2 b = *reinterpret_cast<__half2*>(&u.y);
    float2 fa = __half22float2(a);
    float2 fb = __half22float2(b);
    return make_float4(fa.x, fa.y, fb.x, fb.y);
}

// ---- prep: transpose (B,C,H,W) f32 -> (B,H*W,C) f16 [0..4095]
//            + ROI sort / counter-zero / slack-zero [4096] + per-ROI geometry [4097..4292] ----
__global__ __launch_bounds__(256) void prep(const float* __restrict__ in,
                                            __half* __restrict__ fTh,
                                            const float* __restrict__ rois,
                                            int* __restrict__ perm,
                                            float* __restrict__ roitab,
                                            int* __restrict__ cnt) {
    int bid = blockIdx.x;
    if (bid < 4096) {
        __shared__ float tile[32][33];
        int b   = bid >> 10;
        int rem = bid & 1023;
        int c0  = (rem >> 7) * 32;
        int p0  = (rem & 127) * 32;
        int tx  = threadIdx.x & 31;
        int ty  = threadIdx.x >> 5;
        const float* src = in + (size_t)b * C_ * HW_;
#pragma unroll
        for (int i = 0; i < 32; i += 8)
            tile[ty + i][tx] = src[(size_t)(c0 + ty + i) * HW_ + (p0 + tx)];
        __syncthreads();
        __half2* dsth = (__half2*)(fTh + (size_t)b * HW_ * C_);
#pragma unroll
        for (int i = 0; i < 2; ++i) {
            int idx = threadIdx.x + i * 256;
            int py  = idx >> 4;
            int cp  = idx & 15;
            float lo = tile[cp * 2][py];
            float hi = tile[cp * 2 + 1][py];
            dsth[(size_t)(p0 + py) * (C_ / 2) + (c0 >> 1) + cp] = __floats2half2_rn(lo, hi);
        }
        return;
    }
    if (bid == 4096) {
        if (threadIdx.x >= 64) {
            int t = threadIdx.x - 64;
            if (t < 8) cnt[t << 6] = 0;                      // zero the 8 per-XCD queues
            for (int j = t; j < SLACKH; j += 192)            // zero read-overrun slack
                fTh[(size_t)B_ * HW_ * C_ + j] = __half(0.0f);
            return;
        }
        // 1 wave: ballot-based stable counting sort by (batch, y-band). Deterministic.
        int lane = threadIdx.x;
        unsigned long long below = (1ull << lane) - 1ull;
        int key[16];
#pragma unroll
        for (int i = 0; i < 16; ++i) {
            int idx = i * 64 + lane;
            const float* roi = rois + idx * 5;
            int b = (int)roi[0];
            float yc = (roi[2] + roi[4]) * 0.5f * 0.0625f;
            int yb = min(3, max(0, (int)(yc * 0.0625f)));
            key[i] = b * 4 + yb;
        }
        int cntk[16];
#pragma unroll
        for (int k = 0; k < 16; ++k) cntk[k] = 0;
        for (int i = 0; i < 16; ++i)
#pragma unroll
            for (int k = 0; k < 16; ++k)
                cntk[k] += __popcll(__ballot(key[i] == k));
        int off[16]; int acc = 0;
#pragma unroll
        for (int k = 0; k < 16; ++k) { off[k] = acc; acc += cntk[k]; }
        for (int i = 0; i < 16; ++i) {
#pragma unroll
            for (int k = 0; k < 16; ++k) {
                unsigned long long m = __ballot(key[i] == k);
                if (key[i] == k)
                    perm[off[k] + __popcll(m & below)] = i * 64 + lane;
                off[k] += __popcll(m);
            }
        }
        return;
    }
    // per-bin geometry -> scatter into per-ROI record
    int i = (bid - 4097) * 256 + threadIdx.x;   // 0..50175
    int r  = i / PHW_;
    int k  = i - r * PHW_;
    int ph = k / 7, pw = k - ph * 7;
    const float* roi = rois + r * 5;
    int bb = (int)roi[0];
    float x1 = roi[1] * 0.0625f, y1 = roi[2] * 0.0625f;
    float x2 = roi[3] * 0.0625f, y2 = roi[4] * 0.0625f;
    float rw = fmaxf(x2 - x1, 0.0f), rh = fmaxf(y2 - y1, 0.0f);
    float bw = rw / 7.0f, bh = rh / 7.0f;
    float win = bw * bh;
    float* rt = roitab + (size_t)r * ROIT;

    float wy[7], wx[7];
#pragma unroll
    for (int t = 0; t < 7; ++t) { wy[t] = 0.0f; wx[t] = 0.0f; }
    int w0 = 0, h0 = 0, npy = 0, w00 = 0;
    float invwin = 0.0f;
    if (win > 0.0f) {
        float ws = x1 + bw * (float)pw, we = ws + bw;
        float hs = y1 + bh * (float)ph, he = hs + bh;
        float s0w = floorf(ws), s0h = floorf(hs);
        w0 = (int)s0w; h0 = (int)s0h;
        w00 = (int)floorf(x1);
#pragma unroll
        for (int o = 0; o < 6; ++o) {
            float g0, g1;
            cell_w(hs, he, s0h + (float)o, g0, g1);
            wy[o] += g0; wy[o + 1] += g1;
            cell_w(ws, we, s0w + (float)o, g0, g1);
            wx[o] += g0; wx[o + 1] += g1;
        }
        npy = min(7, max(0, (int)ceilf(he - s0h + 1.0f)));
        int npx = min(7, max(0, (int)ceilf(we - s0w + 1.0f)));
        npy = max(0, min(npy, H_ - h0));
        npx = max(0, min(npx, W_ - w0));
#pragma unroll
        for (int t = 0; t < 7; ++t) {
            if (t >= npx) wx[t] = 0.0f;
            if (t >= npy) wy[t] = 0.0f;
        }
        invwin = 1.0f / win;
    }
    if (ph == 0) {
#pragma unroll
        for (int t = 0; t < 7; ++t) rt[pw * 7 + t] = wx[t];
        rt[49 + pw] = __int_as_float(w0 - w00);
    }
    if (pw == 0) {
#pragma unroll
        for (int t = 0; t < 7; ++t) rt[72 + ph * 8 + t] = wy[t] * invwin;
        rt[64 + ph] = __int_as_float(h0 | (npy << 8));
    }
    if (k == 0) {
        int jlim = 0;
        if (win > 0.0f) {
#pragma unroll
            for (int p = 0; p < 7; ++p) {
                float wsp = x1 + bw * (float)p, wep = wsp + bw;
                float s0wp = floorf(wsp);
                int w0p = (int)s0wp;
                int npxp = min(7, max(0, (int)ceilf(wep - s0wp + 1.0f)));
                npxp = max(0, min(npxp, W_ - w0p));
                jlim = max(jlim, (w0p - w00) + npxp);
            }
        }
        rt[63] = __int_as_float(bb | (w00 << 8) | (jlim << 16));
    }
}

// ---- compute: persistent waves; per-XCD task queues over the locality-sorted order ----
__global__ __launch_bounds__(256) void prroi_rows(const __half* __restrict__ fTh,
                                                  const int* __restrict__ perm,
                                                  const float* __restrict__ roitab,
                                                  int* __restrict__ cnt,
                                                  __half* __restrict__ scr) {
    __shared__ __align__(16) float colw[4][32 * 8];   // per-wave 32 cols x {7 coef + pad}
    int wid  = __builtin_amdgcn_readfirstlane(threadIdx.x >> 6);
    int lane = threadIdx.x & 63;
    float* cwv = colw[wid];
    int xcd = blockIdx.x & 7;

    for (int q = 0; q < 8; ++q) {                     // own queue first, then steal
        int xq = (xcd + q) & 7;
        int* qc = cnt + (xq << 6);
        int tbase = xq * TPX;
        for (;;) {
            int t0 = 0;
            if (lane == 0) t0 = atomicAdd(qc, 1);
            int t = __builtin_amdgcn_readfirstlane(__shfl(t0, 0, 64));
            if (t >= TPX) break;
            int task = tbase + t;
            int rs = task / 7;
            int ph = task - rs * 7;
            int r  = __builtin_amdgcn_readfirstlane(perm[rs]);
            const float* rt = roitab + (size_t)r * ROIT;

#pragma unroll
            for (int u = 0; u < 4; ++u) cwv[lane + u * 64] = 0.0f;
            if (lane < 49) {
                int pw = lane / 7;
                int dx = lane - pw * 7;
                float wxv = rt[lane];
                int d = __float_as_int(rt[49 + pw]);
                cwv[(d + dx) * 8 + pw] = wxv;   // unique (jl,pw) per lane
            }
            int meta = __float_as_int(rt[63]);
            int bb   = meta & 0xff;
            int w00  = (meta >> 8) & 0xff;
            int jlim = (meta >> 16) & 0xff;
            int hm   = __float_as_int(rt[64 + ph]);
            int h0   = hm & 0xff;
            int npy  = (hm >> 8) & 0xff;

            float4 acc[7];
#pragma unroll
            for (int p = 0; p < 7; ++p) acc[p] = make_float4(0.f, 0.f, 0.f, 0.f);

            for (int dy = 0; dy < npy; ++dy) {             // wave-uniform bound
                float wyd = rt[72 + ph * 8 + dy];          // uniform -> scalar load
                const __half* rp = fTh + ((size_t)(bb * HW_ + (h0 + dy) * W_ + w00)) * C_ + lane * 4;
                float4 cacc[7];
#pragma unroll
                for (int p = 0; p < 7; ++p) cacc[p] = make_float4(0.f, 0.f, 0.f, 0.f);
                for (int jl = 0; jl < jlim; jl += 2) {     // 2 columns in flight
                    uint2 va = *(const uint2*)(rp + (size_t)jl * C_);
                    uint2 vb = *(const uint2*)(rp + (size_t)(jl + 1) * C_);  // coef 0 past window
                    float4 ca0 = *(const float4*)(cwv + jl * 8);
                    float4 ca1 = *(const float4*)(cwv + jl * 8 + 4);
                    float4 cb0 = *(const float4*)(cwv + jl * 8 + 8);
                    float4 cb1 = *(const float4*)(cwv + jl * 8 + 12);
                    float4 fa = h4_to_f4(va);
                    float4 fb = h4_to_f4(vb);
#define ACCP(P, CA, CB) { \
    cacc[P].x = fmaf(CA, fa.x, fmaf(CB, fb.x, cacc[P].x)); \
    cacc[P].y = fmaf(CA, fa.y, fmaf(CB, fb.y, cacc[P].y)); \
    cacc[P].z = fmaf(CA, fa.z, fmaf(CB, fb.z, cacc[P].z)); \
    cacc[P].w = fmaf(CA, fa.w, fmaf(CB, fb.w, cacc[P].w)); }
                    ACCP(0, ca0.x, cb0.x); ACCP(1, ca0.y, cb0.y); ACCP(2, ca0.z, cb0.z);
                    ACCP(3, ca0.w, cb0.w); ACCP(4, ca1.x, cb1.x); ACCP(5, ca1.y, cb1.y);
                    ACCP(6, ca1.z, cb1.z);
#undef ACCP
                }
#pragma unroll
                for (int p = 0; p < 7; ++p) {
                    acc[p].x = fmaf(wyd, cacc[p].x, acc[p].x);
                    acc[p].y = fmaf(wyd, cacc[p].y, acc[p].y);
                    acc[p].z = fmaf(wyd, cacc[p].z, acc[p].z);
                    acc[p].w = fmaf(wyd, cacc[p].w, acc[p].w);
                }
            }
            __half* sb = scr + ((size_t)r * PHW_ + ph * 7) * C_ + lane * 4;
#pragma unroll
            for (int p = 0; p < 7; ++p) {
                union { __half2 h2[2]; uint2 u; } pk2;
                pk2.h2[0] = __floats2half2_rn(acc[p].x, acc[p].y);
                pk2.h2[1] = __floats2half2_rn(acc[p].z, acc[p].w);
                *(uint2*)(sb + (size_t)p * C_) = pk2.u;
            }
        }
    }
}

// ---- fixup: per-ROI [k][c] f16 -> [c][k] f32 through padded LDS ----
__global__ __launch_bounds__(256) void fixup(const int* __restrict__ perm,
                                             const __half* __restrict__ scr,
                                             float* __restrict__ out) {
    __shared__ __align__(4) __half lds_h[PHW_ * LROWF];
    int bid  = blockIdx.x;
    int spos = ((bid & 7) << 7) | (bid >> 3);   // XCD-matched bijection over sorted positions
    int r    = perm[spos];
    const unsigned int* src = (const unsigned int*)(scr + (size_t)r * PHW_ * C_);
    for (int j = threadIdx.x; j < PHW_ * (C_ / 2); j += 256) {
        int row = j >> 7;
        int col = j & 127;
        *(unsigned int*)&lds_h[row * LROWF + col * 2] = src[j];
    }
    __syncthreads();
    float* outr = out + (size_t)r * (C_ * PHW_);
#pragma unroll 4
    for (int j = threadIdx.x; j < C_ * PHW_; j += 256) {
        int c = j / PHW_;
        int k = j - c * PHW_;
        outr[j] = __half2float(lds_h[k * LROWF + c]);
    }
}

// ---- fallback: original layout, no workspace ----
__global__ __launch_bounds__(256) void prroi_pool_direct(const float* __restrict__ f,
                                                         const float* __restrict__ rois,
                                                         float* __restrict__ out) {
    int bin = blockIdx.x;
    int r  = bin / PHW_;
    int k  = bin - r * PHW_;
    int ph = k / 7;
    int pw = k - ph * 7;
    int c = threadIdx.x;

    const float* roi = rois + r * 5;
    int bb = (int)roi[0];
    float x1 = roi[1] * 0.0625f, y1 = roi[2] * 0.0625f;
    float x2 = roi[3] * 0.0625f, y2 = roi[4] * 0.0625f;
    float rw = fmaxf(x2 - x1, 0.0f), rh = fmaxf(y2 - y1, 0.0f);
    float bw = rw / 7.0f, bh = rh / 7.0f;
    float win = bw * bh;
    size_t oidx = ((size_t)r * C_ + c) * PHW_ + k;
    if (!(win > 0.0f)) { out[oidx] = 0.0f; return; }

    float ws = x1 + bw * (float)pw, we = ws + bw;
    float hs = y1 + bh * (float)ph, he = hs + bh;
    float s0w = floorf(ws), s0h = floorf(hs);
    int w0 = (int)s0w, h0 = (int)s0h;
    float wy[7], wx[7];
#pragma unroll
    for (int t = 0; t < 7; ++t) { wy[t] = 0.0f; wx[t] = 0.0f; }
#pragma unroll
    for (int o = 0; o < 6; ++o) {
        float g0, g1;
        cell_w(hs, he, s0h + (float)o, g0, g1);
        wy[o] += g0; wy[o + 1] += g1;
        cell_w(ws, we, s0w + (float)o, g0, g1);
        wx[o] += g0; wx[o + 1] += g1;
    }
    int npy = min(7, max(0, (int)ceilf(he - s0h + 1.0f)));
    int npx = min(7, max(0, (int)ceilf(we - s0w + 1.0f)));
    npy = max(0, min(npy, H_ - h0));
    npx = max(0, min(npx, W_ - w0));

    const float* fbc = f + ((size_t)bb * C_ + c) * (H_ * W_);
    float acc = 0.0f;
#pragma unroll
    for (int dy = 0; dy < 7; ++dy) {
        if (dy < npy) {
            float row = 0.0f;
#pragma unroll
            for (int dx = 0; dx < 7; ++dx) {
                if (dx < npx)
                    row = fmaf(wx[dx], fbc[(h0 + dy) * W_ + (w0 + dx)], row);
            }
            acc = fmaf(wy[dy], row, acc);
        }
    }
    out[oidx] = acc / win;
}

extern "C" void kernel_launch(void* const* d_in, const int* in_sizes, int n_in,
                              void* d_out, int out_size, void* d_ws, size_t ws_size,
                              hipStream_t stream) {
    const float* feat = (const float*)d_in[0];
    const float* rois = (const float*)d_in[1];
    float* out = (float*)d_out;

    const size_t fth_b   = (size_t)B_ * HW_ * C_ * sizeof(__half);    //  8,388,608
    const size_t slack_b = (size_t)SLACKH * sizeof(__half);           //      4,096
    const size_t perm_b  = (size_t)R_ * sizeof(int);                  //      4,096
    const size_t rt_b    = (size_t)R_ * ROIT * sizeof(float);         //    524,288
    const size_t cnt_b   = 8 * 64 * sizeof(int);                      //      2,048
    const size_t scr_b   = (size_t)R_ * PHW_ * C_ * sizeof(__half);   // 25,690,112

    if (ws_size >= fth_b + slack_b + perm_b + rt_b + cnt_b + scr_b) {
        __half* fTh  = (__half*)d_ws;
        int*    perm = (int*)((char*)d_ws + fth_b + slack_b);
        float*  rtab = (float*)((char*)d_ws + fth_b + slack_b + perm_b);
        int*    cnt  = (int*)((char*)d_ws + fth_b + slack_b + perm_b + rt_b);
        __half* scr  = (__half*)((char*)d_ws + fth_b + slack_b + perm_b + rt_b + cnt_b);
        prep<<<4293, 256, 0, stream>>>(feat, fTh, rois, perm, rtab, cnt);
        prroi_rows<<<1024, 256, 0, stream>>>(fTh, perm, rtab, cnt, scr);
        fixup<<<R_, 256, 0, stream>>>(perm, scr, out);
    } else {
        prroi_pool_direct<<<R_ * PHW_, 256, 0, stream>>>(feat, rois, out);
    }
}

// Round 12
// 68.321 us; speedup vs baseline: 2.7698x; 1.7324x over previous
//
#include <hip/hip_runtime.h>
#include <hip/hip_fp16.h>

#define R_    1024
#define B_    4
#define C_    256
#define H_    64
#define W_    64
#define HW_   4096
#define PHW_  49
#define ROIT  128      // floats per per-ROI geometry record (512 B)
#define LROWF 258      // fixup LDS row halves (256 + 2 pad)
#define SLACKH 16896   // zeroed halves after fTh (covers one full row + pair overrun)

__device__ __forceinline__ void cell_w(float start, float end, float s, float& g0, float& g1) {
    float y0 = fmaxf(start, s);
    float yl = fmaxf(fminf(end, s + 1.0f), y0);
    float a  = y0 - s;
    float la = yl - s;
    g0 = la - 0.5f * la * la - a + 0.5f * a * a;
    g1 = 0.5f * la * la - 0.5f * a * a;
}

__device__ __forceinline__ float4 h4_to_f4(uint2 u) {
    __half2 a = *reinterpret_cast<__half2*>(&u.x);
    __half2 b = *reinterpret_cast<__half2*>(&u.y);
    float2 fa = __half22float2(a);
    float2 fb = __half22float2(b);
    return make_float4(fa.x, fa.y, fb.x, fb.y);
}

// ---- prep: transpose (B,C,H,W) f32 -> (B,H*W,C) f16 [0..4095]
//            + ROI sort / slack-zero [4096] + per-ROI geometry [4097..4292] ----
__global__ __launch_bounds__(256) void prep(const float* __restrict__ in,
                                            __half* __restrict__ fTh,
                                            const float* __restrict__ rois,
                                            int* __restrict__ perm,
                                            float* __restrict__ roitab) {
    int bid = blockIdx.x;
    if (bid < 4096) {
        __shared__ float tile[32][33];
        int b   = bid >> 10;
        int rem = bid & 1023;
        int c0  = (rem >> 7) * 32;
        int p0  = (rem & 127) * 32;
        int tx  = threadIdx.x & 31;
        int ty  = threadIdx.x >> 5;
        const float* src = in + (size_t)b * C_ * HW_;
#pragma unroll
        for (int i = 0; i < 32; i += 8)
            tile[ty + i][tx] = src[(size_t)(c0 + ty + i) * HW_ + (p0 + tx)];
        __syncthreads();
        __half2* dsth = (__half2*)(fTh + (size_t)b * HW_ * C_);
#pragma unroll
        for (int i = 0; i < 2; ++i) {
            int idx = threadIdx.x + i * 256;
            int py  = idx >> 4;
            int cp  = idx & 15;
            float lo = tile[cp * 2][py];
            float hi = tile[cp * 2 + 1][py];
            dsth[(size_t)(p0 + py) * (C_ / 2) + (c0 >> 1) + cp] = __floats2half2_rn(lo, hi);
        }
        return;
    }
    if (bid == 4096) {
        if (threadIdx.x >= 64) {
            for (int j = threadIdx.x - 64; j < SLACKH; j += 192)
                fTh[(size_t)B_ * HW_ * C_ + j] = __half(0.0f);
            return;
        }
        // 1 wave: ballot-based stable counting sort by (batch, y-band). Deterministic.
        int lane = threadIdx.x;
        unsigned long long below = (1ull << lane) - 1ull;
        int key[16];
#pragma unroll
        for (int i = 0; i < 16; ++i) {
            int idx = i * 64 + lane;
            const float* roi = rois + idx * 5;
            int b = (int)roi[0];
            float yc = (roi[2] + roi[4]) * 0.5f * 0.0625f;
            int yb = min(3, max(0, (int)(yc * 0.0625f)));
            key[i] = b * 4 + yb;
        }
        int cntk[16];
#pragma unroll
        for (int k = 0; k < 16; ++k) cntk[k] = 0;
        for (int i = 0; i < 16; ++i)
#pragma unroll
            for (int k = 0; k < 16; ++k)
                cntk[k] += __popcll(__ballot(key[i] == k));
        int off[16]; int acc = 0;
#pragma unroll
        for (int k = 0; k < 16; ++k) { off[k] = acc; acc += cntk[k]; }
        for (int i = 0; i < 16; ++i) {
#pragma unroll
            for (int k = 0; k < 16; ++k) {
                unsigned long long m = __ballot(key[i] == k);
                if (key[i] == k)
                    perm[off[k] + __popcll(m & below)] = i * 64 + lane;
                off[k] += __popcll(m);
            }
        }
        return;
    }
    // per-bin geometry -> scatter into per-ROI record
    int i = (bid - 4097) * 256 + threadIdx.x;   // 0..50175
    int r  = i / PHW_;
    int k  = i - r * PHW_;
    int ph = k / 7, pw = k - ph * 7;
    const float* roi = rois + r * 5;
    int bb = (int)roi[0];
    float x1 = roi[1] * 0.0625f, y1 = roi[2] * 0.0625f;
    float x2 = roi[3] * 0.0625f, y2 = roi[4] * 0.0625f;
    float rw = fmaxf(x2 - x1, 0.0f), rh = fmaxf(y2 - y1, 0.0f);
    float bw = rw / 7.0f, bh = rh / 7.0f;
    float win = bw * bh;
    float* rt = roitab + (size_t)r * ROIT;

    float wy[8], wx[7];
#pragma unroll
    for (int t = 0; t < 7; ++t) { wy[t] = 0.0f; wx[t] = 0.0f; }
    wy[7] = 0.0f;
    int w0 = 0, h0 = 0, npy = 0, w00 = 0;
    float invwin = 0.0f;
    if (win > 0.0f) {
        float ws = x1 + bw * (float)pw, we = ws + bw;
        float hs = y1 + bh * (float)ph, he = hs + bh;
        float s0w = floorf(ws), s0h = floorf(hs);
        w0 = (int)s0w; h0 = (int)s0h;
        w00 = (int)floorf(x1);
#pragma unroll
        for (int o = 0; o < 6; ++o) {
            float g0, g1;
            cell_w(hs, he, s0h + (float)o, g0, g1);
            wy[o] += g0; wy[o + 1] += g1;
            cell_w(ws, we, s0w + (float)o, g0, g1);
            wx[o] += g0; wx[o + 1] += g1;
        }
        npy = min(7, max(0, (int)ceilf(he - s0h + 1.0f)));
        int npx = min(7, max(0, (int)ceilf(we - s0w + 1.0f)));
        npy = max(0, min(npy, H_ - h0));
        npx = max(0, min(npx, W_ - w0));
#pragma unroll
        for (int t = 0; t < 7; ++t) {
            if (t >= npx) wx[t] = 0.0f;
            if (t >= npy) wy[t] = 0.0f;
        }
        invwin = 1.0f / win;
    }
    if (ph == 0) {
#pragma unroll
        for (int t = 0; t < 7; ++t) rt[pw * 7 + t] = wx[t];
        rt[49 + pw] = __int_as_float(w0 - w00);
    }
    if (pw == 0) {
#pragma unroll
        for (int t = 0; t < 8; ++t) rt[72 + ph * 8 + t] = wy[t] * invwin;   // slot 7 = 0
        rt[64 + ph] = __int_as_float(h0 | (npy << 8));
    }
    if (k == 0) {
        int jlim = 0;
        if (win > 0.0f) {
#pragma unroll
            for (int p = 0; p < 7; ++p) {
                float wsp = x1 + bw * (float)p, wep = wsp + bw;
                float s0wp = floorf(wsp);
                int w0p = (int)s0wp;
                int npxp = min(7, max(0, (int)ceilf(wep - s0wp + 1.0f)));
                npxp = max(0, min(npxp, W_ - w0p));
                jlim = max(jlim, (w0p - w00) + npxp);
            }
        }
        rt[63] = __int_as_float(bb | (w00 << 8) | (jlim << 16));
    }
}

// ---- compute: one wave per (ROI, bin-row), static XCD-chunked.
// Row-combine-first: g_col = sum_dy wy[dy]*f[dy][col]; acc[p] += c[p][col]*g_col.
// 2 cols x 2 rows per step -> 4 independent loads in flight.
__global__ __launch_bounds__(256) void prroi_rows(const __half* __restrict__ fTh,
                                                  const int* __restrict__ perm,
                                                  const float* __restrict__ roitab,
                                                  __half* __restrict__ scr) {
    __shared__ __align__(16) float colw[4][32 * 8];   // per-wave 32 cols x {7 coef + pad}
    int wid  = __builtin_amdgcn_readfirstlane(threadIdx.x >> 6);
    int lane = threadIdx.x & 63;
    float* cwv = colw[wid];
    int bid = blockIdx.x;                               // 1792 blocks
    int g   = (bid & 7) * 896 + (bid >> 3) * 4 + wid;   // XCD-chunked 0..7167
    int rs  = g / 7;
    int ph  = g - rs * 7;
    int r   = __builtin_amdgcn_readfirstlane(perm[rs]);
    const float* rt = roitab + (size_t)r * ROIT;

#pragma unroll
    for (int u = 0; u < 4; ++u) cwv[lane + u * 64] = 0.0f;
    if (lane < 49) {
        int pw = lane / 7;
        int dx = lane - pw * 7;
        float wxv = rt[lane];
        int d = __float_as_int(rt[49 + pw]);
        cwv[(d + dx) * 8 + pw] = wxv;   // unique (jl,pw) per lane
    }
    int meta = __float_as_int(rt[63]);
    int bb   = meta & 0xff;
    int w00  = (meta >> 8) & 0xff;
    int jlim = (meta >> 16) & 0xff;
    int hm   = __float_as_int(rt[64 + ph]);
    int h0   = hm & 0xff;
    int npy  = (hm >> 8) & 0xff;
    int npy2 = (npy + 1) & ~1;          // even round-up; extra row has wy=0, lands in slack
    const float* wyp = rt + 72 + ph * 8;
    const __half* fr = fTh + ((size_t)bb * HW_ + (size_t)h0 * W_ + w00) * C_ + lane * 4;

    float4 acc[7];
#pragma unroll
    for (int p = 0; p < 7; ++p) acc[p] = make_float4(0.f, 0.f, 0.f, 0.f);

    for (int jl = 0; jl < jlim; jl += 2) {
        const __half* cp = fr + (size_t)jl * C_;
        float4 gA = make_float4(0.f, 0.f, 0.f, 0.f);
        float4 gB = make_float4(0.f, 0.f, 0.f, 0.f);
        for (int dy = 0; dy < npy2; dy += 2) {          // wave-uniform bound
            const __half* r0 = cp + (size_t)dy * (W_ * C_);
            uint2 va0 = *(const uint2*)(r0);
            uint2 vb0 = *(const uint2*)(r0 + C_);
            uint2 va1 = *(const uint2*)(r0 + W_ * C_);
            uint2 vb1 = *(const uint2*)(r0 + W_ * C_ + C_);
            float w0y = wyp[dy];                        // scalar loads (uniform)
            float w1y = wyp[dy + 1];                    // slot<=7, zeroed beyond npy
            float4 fa0 = h4_to_f4(va0);
            float4 fb0 = h4_to_f4(vb0);
            float4 fa1 = h4_to_f4(va1);
            float4 fb1 = h4_to_f4(vb1);
            gA.x = fmaf(w0y, fa0.x, fmaf(w1y, fa1.x, gA.x));
            gA.y = fmaf(w0y, fa0.y, fmaf(w1y, fa1.y, gA.y));
            gA.z = fmaf(w0y, fa0.z, fmaf(w1y, fa1.z, gA.z));
            gA.w = fmaf(w0y, fa0.w, fmaf(w1y, fa1.w, gA.w));
            gB.x = fmaf(w0y, fb0.x, fmaf(w1y, fb1.x, gB.x));
            gB.y = fmaf(w0y, fb0.y, fmaf(w1y, fb1.y, gB.y));
            gB.z = fmaf(w0y, fb0.z, fmaf(w1y, fb1.z, gB.z));
            gB.w = fmaf(w0y, fb0.w, fmaf(w1y, fb1.w, gB.w));
        }
        float4 ca0 = *(const float4*)(cwv + jl * 8);        // coefs p0..3, col jl
        float4 ca1 = *(const float4*)(cwv + jl * 8 + 4);    // coefs p4..6 (+pad)
        float4 cb0 = *(const float4*)(cwv + jl * 8 + 8);    // col jl+1
        float4 cb1 = *(const float4*)(cwv + jl * 8 + 12);
#define ACCP(P, CA, CB) { \
    acc[P].x = fmaf(CA, gA.x, fmaf(CB, gB.x, acc[P].x)); \
    acc[P].y = fmaf(CA, gA.y, fmaf(CB, gB.y, acc[P].y)); \
    acc[P].z = fmaf(CA, gA.z, fmaf(CB, gB.z, acc[P].z)); \
    acc[P].w = fmaf(CA, gA.w, fmaf(CB, gB.w, acc[P].w)); }
        ACCP(0, ca0.x, cb0.x); ACCP(1, ca0.y, cb0.y); ACCP(2, ca0.z, cb0.z);
        ACCP(3, ca0.w, cb0.w); ACCP(4, ca1.x, cb1.x); ACCP(5, ca1.y, cb1.y);
        ACCP(6, ca1.z, cb1.z);
#undef ACCP
    }
    __half* sb = scr + ((size_t)r * PHW_ + ph * 7) * C_ + lane * 4;
#pragma unroll
    for (int p = 0; p < 7; ++p) {
        union { __half2 h2[2]; uint2 u; } pk2;
        pk2.h2[0] = __floats2half2_rn(acc[p].x, acc[p].y);
        pk2.h2[1] = __floats2half2_rn(acc[p].z, acc[p].w);
        *(uint2*)(sb + (size_t)p * C_) = pk2.u;
    }
}

// ---- fixup: per-ROI [k][c] f16 -> [c][k] f32 through padded LDS; XCD-matched ----
__global__ __launch_bounds__(256) void fixup(const int* __restrict__ perm,
                                             const __half* __restrict__ scr,
                                             float* __restrict__ out) {
    __shared__ __align__(4) __half lds_h[PHW_ * LROWF];
    int bid  = blockIdx.x;
    int spos = ((bid & 7) << 7) | (bid >> 3);   // same XCD chunk as producer
    int r    = perm[spos];
    const unsigned int* src = (const unsigned int*)(scr + (size_t)r * PHW_ * C_);
    for (int j = threadIdx.x; j < PHW_ * (C_ / 2); j += 256) {
        int row = j >> 7;
        int col = j & 127;
        *(unsigned int*)&lds_h[row * LROWF + col * 2] = src[j];
    }
    __syncthreads();
    float* outr = out + (size_t)r * (C_ * PHW_);
#pragma unroll 4
    for (int j = threadIdx.x; j < C_ * PHW_; j += 256) {
        int c = j / PHW_;
        int k = j - c * PHW_;
        outr[j] = __half2float(lds_h[k * LROWF + c]);
    }
}

// ---- fallback: original layout, no workspace ----
__global__ __launch_bounds__(256) void prroi_pool_direct(const float* __restrict__ f,
                                                         const float* __restrict__ rois,
                                                         float* __restrict__ out) {
    int bin = blockIdx.x;
    int r  = bin / PHW_;
    int k  = bin - r * PHW_;
    int ph = k / 7;
    int pw = k - ph * 7;
    int c = threadIdx.x;

    const float* roi = rois + r * 5;
    int bb = (int)roi[0];
    float x1 = roi[1] * 0.0625f, y1 = roi[2] * 0.0625f;
    float x2 = roi[3] * 0.0625f, y2 = roi[4] * 0.0625f;
    float rw = fmaxf(x2 - x1, 0.0f), rh = fmaxf(y2 - y1, 0.0f);
    float bw = rw / 7.0f, bh = rh / 7.0f;
    float win = bw * bh;
    size_t oidx = ((size_t)r * C_ + c) * PHW_ + k;
    if (!(win > 0.0f)) { out[oidx] = 0.0f; return; }

    float ws = x1 + bw * (float)pw, we = ws + bw;
    float hs = y1 + bh * (float)ph, he = hs + bh;
    float s0w = floorf(ws), s0h = floorf(hs);
    int w0 = (int)s0w, h0 = (int)s0h;
    float wy[7], wx[7];
#pragma unroll
    for (int t = 0; t < 7; ++t) { wy[t] = 0.0f; wx[t] = 0.0f; }
#pragma unroll
    for (int o = 0; o < 6; ++o) {
        float g0, g1;
        cell_w(hs, he, s0h + (float)o, g0, g1);
        wy[o] += g0; wy[o + 1] += g1;
        cell_w(ws, we, s0w + (float)o, g0, g1);
        wx[o] += g0; wx[o + 1] += g1;
    }
    int npy = min(7, max(0, (int)ceilf(he - s0h + 1.0f)));
    int npx = min(7, max(0, (int)ceilf(we - s0w + 1.0f)));
    npy = max(0, min(npy, H_ - h0));
    npx = max(0, min(npx, W_ - w0));

    const float* fbc = f + ((size_t)bb * C_ + c) * (H_ * W_);
    float acc = 0.0f;
#pragma unroll
    for (int dy = 0; dy < 7; ++dy) {
        if (dy < npy) {
            float row = 0.0f;
#pragma unroll
            for (int dx = 0; dx < 7; ++dx) {
                if (dx < npx)
                    row = fmaf(wx[dx], fbc[(h0 + dy) * W_ + (w0 + dx)], row);
            }
            acc = fmaf(wy[dy], row, acc);
        }
    }
    out[oidx] = acc / win;
}

extern "C" void kernel_launch(void* const* d_in, const int* in_sizes, int n_in,
                              void* d_out, int out_size, void* d_ws, size_t ws_size,
                              hipStream_t stream) {
    const float* feat = (const float*)d_in[0];
    const float* rois = (const float*)d_in[1];
    float* out = (float*)d_out;

    const size_t fth_b   = (size_t)B_ * HW_ * C_ * sizeof(__half);    //  8,388,608
    const size_t slack_b = (size_t)SLACKH * sizeof(__half);           //     33,792
    const size_t perm_b  = (size_t)R_ * sizeof(int);                  //      4,096
    const size_t rt_b    = (size_t)R_ * ROIT * sizeof(float);         //    524,288
    const size_t scr_b   = (size_t)R_ * PHW_ * C_ * sizeof(__half);   // 25,690,112

    if (ws_size >= fth_b + slack_b + perm_b + rt_b + scr_b) {
        __half* fTh  = (__half*)d_ws;
        int*    perm = (int*)((char*)d_ws + fth_b + slack_b);
        float*  rtab = (float*)((char*)d_ws + fth_b + slack_b + perm_b);
        __half* scr  = (__half*)((char*)d_ws + fth_b + slack_b + perm_b + rt_b);
        prep<<<4293, 256, 0, stream>>>(feat, fTh, rois, perm, rtab);
        prroi_rows<<<1792, 256, 0, stream>>>(fTh, perm, rtab, scr);
        fixup<<<R_, 256, 0, stream>>>(perm, scr, out);
    } else {
        prroi_pool_direct<<<R_ * PHW_, 256, 0, stream>>>(feat, rois, out);
    }
}